// Round 3
// baseline (277.942 us; speedup 1.0000x reference)
//
#include <hip/hip_runtime.h>
#include <stdint.h>

typedef unsigned short u16;
typedef __attribute__((ext_vector_type(8))) __bf16 bf16x8;
typedef __attribute__((ext_vector_type(4))) float f32x4;
typedef __attribute__((ext_vector_type(8))) u16 u16x8;

#define B_SZ 2
#define T_SZ 2048
#define C_SZ 2048
#define H_SZ 16
#define D_SZ 128
#define NQKV 2304   // C + D + D (q | k | v)
#define ATT_SCALE 0.08838834764831845f
#define DEFER_THR 90.50967f   // 8 / ATT_SCALE : P bounded by e^8

typedef __attribute__((address_space(1))) void* as1_void_p;
typedef __attribute__((address_space(3))) void* as3_void_p;

__device__ __forceinline__ u16 f2b(float f) {
  union { float f; uint32_t u; } c; c.f = f;
  return (u16)((c.u + 0x7FFFu + ((c.u >> 16) & 1u)) >> 16);
}

__device__ __forceinline__ void gload_lds16(const u16* g, u16* l) {
  __builtin_amdgcn_global_load_lds((as1_void_p)g, (as3_void_p)l, 16, 0, 0);
}

// ---------------- cast f32 -> bf16 (vectorized) ----------------
__global__ __launch_bounds__(256) void cast_to_bf16(const float* __restrict__ in,
                                                    u16* __restrict__ out, int n) {
  int idx = (blockIdx.x * 256 + threadIdx.x) * 4;
  if (idx >= n) return;
  float4 f = *(const float4*)&in[idx];
  ushort4 o4;
  o4.x = f2b(f.x); o4.y = f2b(f.y); o4.z = f2b(f.z); o4.w = f2b(f.w);
  *(ushort4*)&out[idx] = o4;
}

__global__ __launch_bounds__(256) void build_bias(const float* __restrict__ bq,
                                                  const float* __restrict__ bk,
                                                  const float* __restrict__ bv,
                                                  float* __restrict__ out) {
  int i = blockIdx.x * 256 + threadIdx.x;
  if (i < C_SZ) out[i] = bq[i];
  else if (i < C_SZ + D_SZ) out[i] = bk[i - C_SZ];
  else if (i < NQKV) out[i] = bv[i - C_SZ - D_SZ];
}

// ---------------- GEMM: C[M,N] = A[M,K] @ Bm[N,K]^T + bias ----------------
// 128x128 tile, BK=32, 4 waves (2x2), each wave 64x64 = 4x4 16x16 frags.
template <typename OutT>
__global__ __launch_bounds__(256) void gemm_bt(const u16* __restrict__ A,
                                               const u16* __restrict__ Bm,
                                               const float* __restrict__ bias,
                                               OutT* __restrict__ C,
                                               int K, int ldc) {
  __shared__ u16 lsA[128 * 32];
  __shared__ u16 lsB[128 * 32];
  const int tid = threadIdx.x;
  const int lane = tid & 63;
  const int wave = tid >> 6;
  const int wr = wave >> 1, wc = wave & 1;
  const int l16 = lane & 15, lq = lane >> 4;
  const int brow = blockIdx.y * 128;
  const int bcol = blockIdx.x * 128;

  f32x4 acc[4][4] = {};

  for (int k0 = 0; k0 < K; k0 += 32) {
    __syncthreads();  // previous iteration's LDS reads complete
#pragma unroll
    for (int i = 0; i < 2; i++) {
      const int woff = (i * 4 + wave) * 512;   // elem offset of this wave's 1KB chunk
      const int eoff = woff + lane * 8;
      const int r = eoff >> 5, c = eoff & 31;
      gload_lds16(A + (size_t)(brow + r) * K + k0 + c, &lsA[woff]);
      gload_lds16(Bm + (size_t)(bcol + r) * K + k0 + c, &lsB[woff]);
    }
    __syncthreads();  // vmcnt(0) drained by compiler before barrier

    bf16x8 af[4], bfr[4];
#pragma unroll
    for (int mi = 0; mi < 4; mi++)
      af[mi] = *(const bf16x8*)&lsA[(wr * 64 + mi * 16 + l16) * 32 + lq * 8];
#pragma unroll
    for (int ni = 0; ni < 4; ni++)
      bfr[ni] = *(const bf16x8*)&lsB[(wc * 64 + ni * 16 + l16) * 32 + lq * 8];
#pragma unroll
    for (int mi = 0; mi < 4; mi++)
#pragma unroll
      for (int ni = 0; ni < 4; ni++)
        acc[mi][ni] = __builtin_amdgcn_mfma_f32_16x16x32_bf16(af[mi], bfr[ni], acc[mi][ni], 0, 0, 0);
  }

#pragma unroll
  for (int mi = 0; mi < 4; mi++)
#pragma unroll
    for (int ni = 0; ni < 4; ni++) {
      const int col = bcol + wc * 64 + ni * 16 + l16;
      const float bb = bias ? bias[col] : 0.0f;
#pragma unroll
      for (int r = 0; r < 4; r++) {
        const int row = brow + wr * 64 + mi * 16 + lq * 4 + r;  // C/D: row=(l>>4)*4+reg, col=l&15
        const float v = acc[mi][ni][r] + bb;
        if constexpr (sizeof(OutT) == 2) {
          ((u16*)C)[(size_t)row * ldc + col] = f2b(v);
        } else {
          ((float*)C)[(size_t)row * ldc + col] = v;
        }
      }
    }
}

// ---------------- transpose V: vT[b][d][t] = qkv[b*T+t][2176+d] ----------------
__global__ __launch_bounds__(256) void transpose_v(const u16* __restrict__ qkv,
                                                   u16* __restrict__ vT) {
  __shared__ u16 tile[64 * 136];  // [t][d], row stride 136 (16B aligned, depads banks)
  const int tid = threadIdx.x;
  const int t0 = blockIdx.x * 64;
  const int b = blockIdx.y;
#pragma unroll
  for (int i = 0; i < 4; i++) {
    int idx = (i * 256 + tid) * 8;
    int r = idx >> 7, c = idx & 127;
    u16x8 v = *(const u16x8*)&qkv[(size_t)(b * T_SZ + t0 + r) * NQKV + (C_SZ + D_SZ) + c];
    *(u16x8*)&tile[r * 136 + c] = v;
  }
  __syncthreads();
#pragma unroll
  for (int i = 0; i < 4; i++) {
    int idx = (i * 256 + tid) * 8;
    int d = idx >> 6, t = idx & 63;
    u16x8 v;
#pragma unroll
    for (int j = 0; j < 8; j++) v[j] = tile[(t + j) * 136 + d];
    *(u16x8*)&vT[(size_t)(b * D_SZ + d) * T_SZ + t0 + t] = v;
  }
}

// ---------------- flash attention 32-kv tile consume (per wave) ----------------
// lk: [32 kv][128 d] bf16, chunk-swizzled c ^= row&7 (16B chunks)
// lv: [128 d][32 t]  bf16, chunk-swizzled c ^= row&3
// lsPw: per-wave [16 q][32 s], chunk-swizzled c ^= qrow&3
// Softmax state: mgrp = running max of this lane's 16-lane group (rows lq*4..+3,
// uniform across the group; any row-uniform m >= rowmax is valid). lp[rr] =
// per-lane PARTIAL row sum (reduced across lanes only at epilogue).
template <bool MASK>
__device__ __forceinline__ void attn_tile32(
    const u16* lk, const u16* lv, u16* lsPw,
    const bf16x8 (&aq)[4], f32x4 (&o)[8], float (&lp)[4], float& mgrp,
    int relq, int l16, int lq)
{
  f32x4 s[2] = {};
#pragma unroll
  for (int kk = 0; kk < 4; kk++) {
#pragma unroll
    for (int nb = 0; nb < 2; nb++) {
      const int row = nb * 16 + l16;
      const bf16x8 bk = *(const bf16x8*)&lk[row * 128 + (((kk * 4 + lq) ^ (row & 7)) << 3)];
      s[nb] = __builtin_amdgcn_mfma_f32_16x16x32_bf16(aq[kk], bk, s[nb], 0, 0, 0);
    }
  }
  if (MASK) {
#pragma unroll
    for (int nb = 0; nb < 2; nb++)
#pragma unroll
      for (int rr = 0; rr < 4; rr++)
        if (nb * 16 + l16 > relq + rr) s[nb][rr] -= 1e9f;  // additive causal mask
  }
  // group max (one tree for the 4 rows of this 16-lane group)
  float mx = fmaxf(fmaxf(fmaxf(s[0][0], s[0][1]), fmaxf(s[0][2], s[0][3])),
                   fmaxf(fmaxf(s[1][0], s[1][1]), fmaxf(s[1][2], s[1][3])));
#pragma unroll
  for (int sh = 8; sh >= 1; sh >>= 1) mx = fmaxf(mx, __shfl_xor(mx, sh, 64));
  // defer-max: rescale only when the group max grew enough to matter
  if (__any(mx > mgrp + DEFER_THR)) {
    const float mnew = fmaxf(mgrp, mx);
    const float alpha = __expf((mgrp - mnew) * ATT_SCALE);
    mgrp = mnew;
#pragma unroll
    for (int rr = 0; rr < 4; rr++) lp[rr] *= alpha;
#pragma unroll
    for (int nd = 0; nd < 8; nd++)
#pragma unroll
      for (int e = 0; e < 4; e++) o[nd][e] *= alpha;
  }
  // p = exp((s - m) * scale); accumulate partial row sums; write P to LDS
#pragma unroll
  for (int nb = 0; nb < 2; nb++)
#pragma unroll
    for (int rr = 0; rr < 4; rr++) {
      const float p = __expf((s[nb][rr] - mgrp) * ATT_SCALE);
      lp[rr] += p;
      const int qr = lq * 4 + rr;
      const int col = nb * 16 + l16;
      lsPw[qr * 32 + ((((col >> 3) ^ (qr & 3)) << 3) | (col & 7))] = f2b(p);
    }
  asm volatile("s_waitcnt lgkmcnt(0)" ::: "memory");
  __builtin_amdgcn_sched_barrier(0);
  // PV: one K=32 MFMA per 16-wide d block
  const bf16x8 pa = *(const bf16x8*)&lsPw[l16 * 32 + ((lq ^ (l16 & 3)) << 3)];
#pragma unroll
  for (int nd = 0; nd < 8; nd++) {
    const int row = nd * 16 + l16;
    const bf16x8 bv = *(const bf16x8*)&lv[row * 32 + ((lq ^ (row & 3)) << 3)];
    o[nd] = __builtin_amdgcn_mfma_f32_16x16x32_bf16(pa, bv, o[nd], 0, 0, 0);
  }
}

// ---------------- flash attention, causal, MQA ----------------
// grid (32, H, B), heavy-first (qt = 31 - bx). Block = 4 waves x 16 q rows = one
// 64-row q tile. KVBLK=32, K/V double-buffered LDS (36KB total -> 4 blocks/CU).
__global__ __launch_bounds__(256, 4) void attn_fwd(const u16* __restrict__ qkv,
                                                   const u16* __restrict__ vT,
                                                   u16* __restrict__ out) {
  __shared__ u16 lsK[2][32 * 128];
  __shared__ u16 lsV[2][128 * 32];
  __shared__ u16 lsP[4][16 * 32];
  const int tid = threadIdx.x;
  const int w = tid >> 6, lane = tid & 63;
  const int l16 = lane & 15, lq = lane >> 4;
  const int qt = 31 - blockIdx.x;     // heavy blocks launch first
  const int h = blockIdx.y;
  const int b = blockIdx.z;
  const int bT = b * T_SZ;
  const int wq0 = qt * 64 + w * 16;   // this wave's first q row

  bf16x8 aq[4];
  {
    const size_t qrow = (size_t)(bT + wq0 + l16) * NQKV + h * D_SZ;
#pragma unroll
    for (int kk = 0; kk < 4; kk++)
      aq[kk] = *(const bf16x8*)&qkv[qrow + kk * 32 + lq * 8];
  }

  f32x4 o[8] = {};
  float lp[4] = {0.f, 0.f, 0.f, 0.f};
  float mgrp = -INFINITY;

  auto STAGE = [&](int kt, int bufsel) {
    const int kv0 = kt << 5;
#pragma unroll
    for (int j = 0; j < 2; j++) {
      const int idx = w * 128 + j * 64 + lane;
      {  // K tile: 32 rows x 16 chunks of 16B
        const int row = idx >> 4, c = idx & 15;
        const int sc = c ^ (row & 7);
        gload_lds16(qkv + (size_t)(bT + kv0 + row) * NQKV + C_SZ + sc * 8,
                    &lsK[bufsel][(w * 128 + j * 64) * 8]);
      }
      {  // V tile: 128 d rows x 4 chunks
        const int row = idx >> 2, c = idx & 3;
        const int sc = c ^ (row & 3);
        gload_lds16(vT + (size_t)(b * D_SZ + row) * T_SZ + kv0 + sc * 8,
                    &lsV[bufsel][(w * 128 + j * 64) * 8]);
      }
    }
  };

  const int nkt = 2 * qt + 2;
  STAGE(0, 0);
  __syncthreads();   // compiler drains vmcnt(0) before barrier
  int cur = 0;
  for (int kt = 0; kt < nkt; kt++) {
    const int kv0 = kt << 5;
    if (kt + 1 < nkt) STAGE(kt + 1, cur ^ 1);   // prefetch overlaps compute
    if (kv0 + 31 <= wq0) {
      attn_tile32<false>(lsK[cur], lsV[cur], lsP[w], aq, o, lp, mgrp,
                         0, l16, lq);
    } else if (kv0 <= wq0 + 15) {
      attn_tile32<true>(lsK[cur], lsV[cur], lsP[w], aq, o, lp, mgrp,
                        wq0 - kv0 + lq * 4, l16, lq);
    }
    // else: tile entirely in the future for this wave -> skip compute
    __syncthreads();  // prefetch landed + all waves done reading cur
    cur ^= 1;
  }

  // epilogue: reduce the deferred row sums once, then normalize and store
  float lr[4];
#pragma unroll
  for (int rr = 0; rr < 4; rr++) {
    float l = lp[rr];
#pragma unroll
    for (int sh = 8; sh >= 1; sh >>= 1) l += __shfl_xor(l, sh, 64);
    lr[rr] = l;
  }
#pragma unroll
  for (int nd = 0; nd < 8; nd++)
#pragma unroll
    for (int rr = 0; rr < 4; rr++) {
      const int row = wq0 + lq * 4 + rr;
      out[(size_t)(bT + row) * C_SZ + h * D_SZ + nd * 16 + l16] = f2b(o[nd][rr] / lr[rr]);
    }
}

extern "C" void kernel_launch(void* const* d_in, const int* in_sizes, int n_in,
                              void* d_out, int out_size, void* d_ws, size_t ws_size,
                              hipStream_t stream) {
  const float* x  = (const float*)d_in[0];
  // d_in[1] = attn_mask: causal, hardcoded in attn_fwd
  const float* Wq = (const float*)d_in[2];
  const float* bq = (const float*)d_in[3];
  const float* Wk = (const float*)d_in[4];
  const float* bk = (const float*)d_in[5];
  const float* Wv = (const float*)d_in[6];
  const float* bv = (const float*)d_in[7];
  const float* Wo = (const float*)d_in[8];
  const float* bo = (const float*)d_in[9];
  float* out = (float*)d_out;

  // workspace layout (bytes), all 256-aligned
  char* ws = (char*)d_ws;
  if (ws_size < 71312384) return;  // need ~68 MB
  u16* xb     = (u16*)(ws + 0);          // 4096x2048 bf16
  u16* wqkv   = (u16*)(ws + 16777216);   // 2304x2048 bf16 (Wq|Wk|Wv rows)
  u16* wob    = (u16*)(ws + 26214400);   // 2048x2048 bf16
  u16* qkv    = (u16*)(ws + 34603008);   // 4096x2304 bf16
  u16* vT     = (u16*)(ws + 53477376);   // 2x128x2048 bf16
  u16* ao     = (u16*)(ws + 54525952);   // 4096x2048 bf16
  float* bqkv = (float*)(ws + 71303168); // 2304 f32

  cast_to_bf16<<<8192, 256, 0, stream>>>(x, xb, 8388608);
  cast_to_bf16<<<4096, 256, 0, stream>>>(Wq, wqkv, 4194304);
  cast_to_bf16<<<256, 256, 0, stream>>>(Wk, wqkv + 4194304, 262144);
  cast_to_bf16<<<256, 256, 0, stream>>>(Wv, wqkv + 4456448, 262144);
  cast_to_bf16<<<4096, 256, 0, stream>>>(Wo, wob, 4194304);
  build_bias<<<9, 256, 0, stream>>>(bq, bk, bv, bqkv);

  // qkv = xb @ wqkv^T + bias   [4096, 2304]
  gemm_bt<u16><<<dim3(18, 32), 256, 0, stream>>>(xb, wqkv, bqkv, qkv, 2048, NQKV);
  transpose_v<<<dim3(32, 2), 256, 0, stream>>>(qkv, vT);
  attn_fwd<<<dim3(32, 16, 2), 256, 0, stream>>>(qkv, vT, ao);
  // out = ao @ wob^T + bo      [4096, 2048] fp32
  gemm_bt<float><<<dim3(16, 32), 256, 0, stream>>>(ao, wob, bo, out, 2048, 2048);
}

// Round 4
// 225.061 us; speedup vs baseline: 1.2350x; 1.2350x over previous
//
#include <hip/hip_runtime.h>
#include <stdint.h>

typedef unsigned short u16;
typedef __attribute__((ext_vector_type(8))) __bf16 bf16x8;
typedef __attribute__((ext_vector_type(4))) float f32x4;
typedef __attribute__((ext_vector_type(8))) u16 u16x8;

#define B_SZ 2
#define T_SZ 2048
#define C_SZ 2048
#define H_SZ 16
#define D_SZ 128
#define NQKV 2304   // C + D + D (q | k | v)
#define ATT_SCALE 0.08838834764831845f
#define LOG2E_SCALE 0.12751744f     // ATT_SCALE * log2(e)
#define DEFER_THR 90.50967f         // 8 / ATT_SCALE : P bounded by e^8

typedef __attribute__((address_space(1))) void* as1_void_p;
typedef __attribute__((address_space(3))) void* as3_void_p;

__device__ __forceinline__ u16 f2b(float f) {
  union { float f; uint32_t u; } c; c.f = f;
  return (u16)((c.u + 0x7FFFu + ((c.u >> 16) & 1u)) >> 16);
}

__device__ __forceinline__ void gload_lds16(const u16* g, u16* l) {
  __builtin_amdgcn_global_load_lds((as1_void_p)g, (as3_void_p)l, 16, 0, 0);
}

// ---------------- cast f32 -> bf16 (vectorized) ----------------
__global__ __launch_bounds__(256) void cast_to_bf16(const float* __restrict__ in,
                                                    u16* __restrict__ out, int n) {
  int idx = (blockIdx.x * 256 + threadIdx.x) * 4;
  if (idx >= n) return;
  float4 f = *(const float4*)&in[idx];
  ushort4 o4;
  o4.x = f2b(f.x); o4.y = f2b(f.y); o4.z = f2b(f.z); o4.w = f2b(f.w);
  *(ushort4*)&out[idx] = o4;
}

__global__ __launch_bounds__(256) void build_bias(const float* __restrict__ bq,
                                                  const float* __restrict__ bk,
                                                  const float* __restrict__ bv,
                                                  float* __restrict__ out) {
  int i = blockIdx.x * 256 + threadIdx.x;
  if (i < C_SZ) out[i] = bq[i];
  else if (i < C_SZ + D_SZ) out[i] = bk[i - C_SZ];
  else if (i < NQKV) out[i] = bv[i - C_SZ - D_SZ];
}

// ---------------- GEMM: C[M,N] = A[M,K] @ Bm[N,K]^T + bias ----------------
// 128x128 tile, BK=32, 4 waves (2x2), 2-phase pipeline: STAGE(next) issued
// before ds_read+MFMA(cur); loads fly under compute; one barrier per K-step.
template <typename OutT>
__global__ __launch_bounds__(256) void gemm_bt(const u16* __restrict__ A,
                                               const u16* __restrict__ Bm,
                                               const float* __restrict__ bias,
                                               OutT* __restrict__ C,
                                               int K, int ldc) {
  __shared__ u16 lsA[2][128 * 32];
  __shared__ u16 lsB[2][128 * 32];
  const int tid = threadIdx.x;
  const int lane = tid & 63;
  const int wave = tid >> 6;
  const int wr = wave >> 1, wc = wave & 1;
  const int l16 = lane & 15, lq = lane >> 4;
  const int brow = blockIdx.y * 128;
  const int bcol = blockIdx.x * 128;

  f32x4 acc[4][4] = {};

  auto STAGE = [&](int k0, int bs) {
#pragma unroll
    for (int i = 0; i < 2; i++) {
      const int woff = (i * 4 + wave) * 512;   // elem offset of this wave's 1KB chunk
      const int eoff = woff + lane * 8;
      const int r = eoff >> 5, c = eoff & 31;
      gload_lds16(A + (size_t)(brow + r) * K + k0 + c, &lsA[bs][woff]);
      gload_lds16(Bm + (size_t)(bcol + r) * K + k0 + c, &lsB[bs][woff]);
    }
  };

  STAGE(0, 0);
  __syncthreads();  // compiler drains vmcnt(0) before barrier
  int cur = 0;
  for (int k0 = 0; k0 < K; k0 += 32) {
    if (k0 + 32 < K) STAGE(k0 + 32, cur ^ 1);   // prefetch flies under MFMA

    bf16x8 af[4], bfr[4];
#pragma unroll
    for (int mi = 0; mi < 4; mi++)
      af[mi] = *(const bf16x8*)&lsA[cur][(wr * 64 + mi * 16 + l16) * 32 + lq * 8];
#pragma unroll
    for (int ni = 0; ni < 4; ni++)
      bfr[ni] = *(const bf16x8*)&lsB[cur][(wc * 64 + ni * 16 + l16) * 32 + lq * 8];
#pragma unroll
    for (int mi = 0; mi < 4; mi++)
#pragma unroll
      for (int ni = 0; ni < 4; ni++)
        acc[mi][ni] = __builtin_amdgcn_mfma_f32_16x16x32_bf16(af[mi], bfr[ni], acc[mi][ni], 0, 0, 0);

    __syncthreads();  // prefetch landed + all waves done reading cur
    cur ^= 1;
  }

#pragma unroll
  for (int mi = 0; mi < 4; mi++)
#pragma unroll
    for (int ni = 0; ni < 4; ni++) {
      const int col = bcol + wc * 64 + ni * 16 + l16;
      const float bb = bias ? bias[col] : 0.0f;
#pragma unroll
      for (int r = 0; r < 4; r++) {
        const int row = brow + wr * 64 + mi * 16 + lq * 4 + r;  // C/D: row=(l>>4)*4+reg, col=l&15
        const float v = acc[mi][ni][r] + bb;
        if constexpr (sizeof(OutT) == 2) {
          ((u16*)C)[(size_t)row * ldc + col] = f2b(v);
        } else {
          ((float*)C)[(size_t)row * ldc + col] = v;
        }
      }
    }
}

// ---------------- transpose V: vT[b][d][t] = qkv[b*T+t][2176+d] ----------------
__global__ __launch_bounds__(256) void transpose_v(const u16* __restrict__ qkv,
                                                   u16* __restrict__ vT) {
  __shared__ u16 tile[64 * 136];  // [t][d], row stride 136 (16B aligned, depads banks)
  const int tid = threadIdx.x;
  const int t0 = blockIdx.x * 64;
  const int b = blockIdx.y;
#pragma unroll
  for (int i = 0; i < 4; i++) {
    int idx = (i * 256 + tid) * 8;
    int r = idx >> 7, c = idx & 127;
    u16x8 v = *(const u16x8*)&qkv[(size_t)(b * T_SZ + t0 + r) * NQKV + (C_SZ + D_SZ) + c];
    *(u16x8*)&tile[r * 136 + c] = v;
  }
  __syncthreads();
#pragma unroll
  for (int i = 0; i < 4; i++) {
    int idx = (i * 256 + tid) * 8;
    int d = idx >> 6, t = idx & 63;
    u16x8 v;
#pragma unroll
    for (int j = 0; j < 8; j++) v[j] = tile[(t + j) * 136 + d];
    *(u16x8*)&vT[(size_t)(b * D_SZ + d) * T_SZ + t0 + t] = v;
  }
}

// ---------------- flash attention 64-kv tile consume (per wave) ----------------
// lk: [64 kv][128 d] bf16, chunk-swizzled c ^= row&7 (16B chunks)
// lv: [128 d][64 t]  bf16, chunk-swizzled c ^= row&7
// lsPw: per-wave [16 q][64 s], chunk-swizzled c ^= qrow&7
// Softmax: mgrp = running group max (uniform over the 16-lane group; any
// row-uniform m >= rowmax is valid). lp[rr] = per-lane PARTIAL row sums,
// reduced across lanes only at the kernel epilogue. Rescale deferred (T13).
template <bool MASK>
__device__ __forceinline__ void attn_tile64(
    const u16* lk, const u16* lv, u16* lsPw,
    const bf16x8 (&aq)[4], f32x4 (&o)[8], float (&lp)[4], float& mgrp,
    int relq, int l16, int lq)
{
  f32x4 s[4] = {};
#pragma unroll
  for (int kk = 0; kk < 4; kk++) {
#pragma unroll
    for (int nb = 0; nb < 4; nb++) {
      const int row = nb * 16 + l16;
      const bf16x8 bk = *(const bf16x8*)&lk[row * 128 + (((kk * 4 + lq) ^ (row & 7)) << 3)];
      s[nb] = __builtin_amdgcn_mfma_f32_16x16x32_bf16(aq[kk], bk, s[nb], 0, 0, 0);
    }
  }
  if (MASK) {
#pragma unroll
    for (int nb = 0; nb < 4; nb++)
#pragma unroll
      for (int rr = 0; rr < 4; rr++)
        if (nb * 16 + l16 > relq + rr) s[nb][rr] -= 1e9f;  // additive causal mask
  }
  // group max: one tree for the 4 rows owned by this 16-lane group
  float mx = s[0][0];
#pragma unroll
  for (int nb = 0; nb < 4; nb++)
#pragma unroll
    for (int rr = 0; rr < 4; rr++) mx = fmaxf(mx, s[nb][rr]);
#pragma unroll
  for (int sh = 8; sh >= 1; sh >>= 1) mx = fmaxf(mx, __shfl_xor(mx, sh, 64));
  // defer-max: rescale only when the group max grew enough to matter
  if (__any(mx > mgrp + DEFER_THR)) {
    const float mnew = fmaxf(mgrp, mx);
    const float alpha = exp2f((mgrp - mnew) * LOG2E_SCALE);
    mgrp = mnew;
#pragma unroll
    for (int rr = 0; rr < 4; rr++) lp[rr] *= alpha;
#pragma unroll
    for (int nd = 0; nd < 8; nd++)
#pragma unroll
      for (int e = 0; e < 4; e++) o[nd][e] *= alpha;
  }
  // p = exp2((s - m) * scale*log2e); partial row sums; write P to LDS
#pragma unroll
  for (int nb = 0; nb < 4; nb++)
#pragma unroll
    for (int rr = 0; rr < 4; rr++) {
      const float p = exp2f((s[nb][rr] - mgrp) * LOG2E_SCALE);
      lp[rr] += p;
      const int qr = lq * 4 + rr;
      const int col = nb * 16 + l16;
      lsPw[qr * 64 + ((((col >> 3) ^ (qr & 7)) << 3) | (col & 7))] = f2b(p);
    }
  asm volatile("s_waitcnt lgkmcnt(0)" ::: "memory");
  __builtin_amdgcn_sched_barrier(0);
#pragma unroll
  for (int ks = 0; ks < 2; ks++) {
    const bf16x8 pa = *(const bf16x8*)&lsPw[l16 * 64 + (((ks * 4 + lq) ^ (l16 & 7)) << 3)];
#pragma unroll
    for (int nd = 0; nd < 8; nd++) {
      const int row = nd * 16 + l16;
      const bf16x8 bv = *(const bf16x8*)&lv[row * 64 + (((ks * 4 + lq) ^ (row & 7)) << 3)];
      o[nd] = __builtin_amdgcn_mfma_f32_16x16x32_bf16(pa, bv, o[nd], 0, 0, 0);
    }
  }
}

// ---------------- flash attention, causal, MQA, paired q-tiles ----------------
// grid (16, H, B); block handles q-tiles qL=x and qH=31-x -> 33 tile-consumes
// per block = perfect per-CU balance. 4 waves; K/V double-buffered LDS (72KB).
__global__ __launch_bounds__(256, 2) void attn_fwd(const u16* __restrict__ qkv,
                                                   const u16* __restrict__ vT,
                                                   u16* __restrict__ out) {
  __shared__ u16 lsK[2][64 * 128];
  __shared__ u16 lsV[2][128 * 64];
  __shared__ u16 lsP[4][16 * 64];
  const int tid = threadIdx.x;
  const int w = tid >> 6, lane = tid & 63;
  const int l16 = lane & 15, lq = lane >> 4;
  const int qL = blockIdx.x;        // [0,16)
  const int qH = 31 - qL;           // [16,32)
  const int h = blockIdx.y;
  const int b = blockIdx.z;
  const int bT = b * T_SZ;

  bf16x8 aqL[4], aqH[4];
  {
    const size_t rL = (size_t)(bT + qL * 64 + w * 16 + l16) * NQKV + h * D_SZ;
    const size_t rH = (size_t)(bT + qH * 64 + w * 16 + l16) * NQKV + h * D_SZ;
#pragma unroll
    for (int kk = 0; kk < 4; kk++) {
      aqL[kk] = *(const bf16x8*)&qkv[rL + kk * 32 + lq * 8];
      aqH[kk] = *(const bf16x8*)&qkv[rH + kk * 32 + lq * 8];
    }
  }

  f32x4 oL[8] = {}, oH[8] = {};
  float lpL[4] = {0.f, 0.f, 0.f, 0.f};
  float lpH[4] = {0.f, 0.f, 0.f, 0.f};
  float mL = -INFINITY, mH = -INFINITY;
  const int relDiag = w * 16 + lq * 4;   // diag-tile row offset for this lane

  auto STAGE = [&](int kt, int bufsel) {
    const int kv0 = kt << 6;
    // K tile: 64 rows x 16 chunks of 16B; wave w stages rows [w*16, w*16+16)
#pragma unroll
    for (int j = 0; j < 4; j++) {
      const int idx = w * 256 + j * 64 + lane;
      const int row = idx >> 4, c = idx & 15;
      const int sc = c ^ (row & 7);
      gload_lds16(qkv + (size_t)(bT + kv0 + row) * NQKV + C_SZ + sc * 8,
                  &lsK[bufsel][w * 2048 + j * 512]);
    }
    // V tile: 128 rows(d) x 8 chunks; wave w stages rows [w*32, w*32+32)
#pragma unroll
    for (int j = 0; j < 4; j++) {
      const int idx = w * 256 + j * 64 + lane;
      const int row = idx >> 3, c = idx & 7;
      const int sc = c ^ (row & 7);
      gload_lds16(vT + (size_t)(b * D_SZ + row) * T_SZ + kv0 + sc * 8,
                  &lsV[bufsel][w * 2048 + j * 512]);
    }
  };

  STAGE(0, 0);
  __syncthreads();   // compiler drains vmcnt(0) before barrier
  int cur = 0;
  for (int kt = 0; kt <= qH; kt++) {
    if (kt < qH) STAGE(kt + 1, cur ^ 1);       // prefetch overlaps compute
    if (kt == qH)
      attn_tile64<true>(lsK[cur], lsV[cur], lsP[w], aqH, oH, lpH, mH, relDiag, l16, lq);
    else
      attn_tile64<false>(lsK[cur], lsV[cur], lsP[w], aqH, oH, lpH, mH, 0, l16, lq);
    if (kt == qL)
      attn_tile64<true>(lsK[cur], lsV[cur], lsP[w], aqL, oL, lpL, mL, relDiag, l16, lq);
    else if (kt < qL)
      attn_tile64<false>(lsK[cur], lsV[cur], lsP[w], aqL, oL, lpL, mL, 0, l16, lq);
    __syncthreads();  // prefetch landed + all waves done reading cur
    cur ^= 1;
  }

  // epilogue: reduce deferred row sums once, then normalize and store
  float rL4[4], rH4[4];
#pragma unroll
  for (int rr = 0; rr < 4; rr++) {
    float a = lpL[rr], c = lpH[rr];
#pragma unroll
    for (int sh = 8; sh >= 1; sh >>= 1) {
      a += __shfl_xor(a, sh, 64);
      c += __shfl_xor(c, sh, 64);
    }
    rL4[rr] = __builtin_amdgcn_rcpf(a);
    rH4[rr] = __builtin_amdgcn_rcpf(c);
  }
#pragma unroll
  for (int nd = 0; nd < 8; nd++)
#pragma unroll
    for (int rr = 0; rr < 4; rr++) {
      const int rL_ = qL * 64 + w * 16 + lq * 4 + rr;
      const int rH_ = qH * 64 + w * 16 + lq * 4 + rr;
      out[(size_t)(bT + rL_) * C_SZ + h * D_SZ + nd * 16 + l16] = f2b(oL[nd][rr] * rL4[rr]);
      out[(size_t)(bT + rH_) * C_SZ + h * D_SZ + nd * 16 + l16] = f2b(oH[nd][rr] * rH4[rr]);
    }
}

extern "C" void kernel_launch(void* const* d_in, const int* in_sizes, int n_in,
                              void* d_out, int out_size, void* d_ws, size_t ws_size,
                              hipStream_t stream) {
  const float* x  = (const float*)d_in[0];
  // d_in[1] = attn_mask: causal, hardcoded in attn_fwd
  const float* Wq = (const float*)d_in[2];
  const float* bq = (const float*)d_in[3];
  const float* Wk = (const float*)d_in[4];
  const float* bk = (const float*)d_in[5];
  const float* Wv = (const float*)d_in[6];
  const float* bv = (const float*)d_in[7];
  const float* Wo = (const float*)d_in[8];
  const float* bo = (const float*)d_in[9];
  float* out = (float*)d_out;

  // workspace layout (bytes), all 256-aligned
  char* ws = (char*)d_ws;
  if (ws_size < 71312384) return;  // need ~68 MB
  u16* xb     = (u16*)(ws + 0);          // 4096x2048 bf16
  u16* wqkv   = (u16*)(ws + 16777216);   // 2304x2048 bf16 (Wq|Wk|Wv rows)
  u16* wob    = (u16*)(ws + 26214400);   // 2048x2048 bf16
  u16* qkv    = (u16*)(ws + 34603008);   // 4096x2304 bf16
  u16* vT     = (u16*)(ws + 53477376);   // 2x128x2048 bf16
  u16* ao     = (u16*)(ws + 54525952);   // 4096x2048 bf16
  float* bqkv = (float*)(ws + 71303168); // 2304 f32

  cast_to_bf16<<<8192, 256, 0, stream>>>(x, xb, 8388608);
  cast_to_bf16<<<4096, 256, 0, stream>>>(Wq, wqkv, 4194304);
  cast_to_bf16<<<256, 256, 0, stream>>>(Wk, wqkv + 4194304, 262144);
  cast_to_bf16<<<256, 256, 0, stream>>>(Wv, wqkv + 4456448, 262144);
  cast_to_bf16<<<4096, 256, 0, stream>>>(Wo, wob, 4194304);
  build_bias<<<9, 256, 0, stream>>>(bq, bk, bv, bqkv);

  // qkv = xb @ wqkv^T + bias   [4096, 2304]
  gemm_bt<u16><<<dim3(18, 32), 256, 0, stream>>>(xb, wqkv, bqkv, qkv, 2048, NQKV);
  transpose_v<<<dim3(32, 2), 256, 0, stream>>>(qkv, vT);
  attn_fwd<<<dim3(16, 16, 2), 256, 0, stream>>>(qkv, vT, ao);
  // out = ao @ wob^T + bo      [4096, 2048] fp32
  gemm_bt<float><<<dim3(16, 32), 256, 0, stream>>>(ao, wob, bo, out, 2048, 2048);
}